// Round 6
// baseline (49.995 us; speedup 1.0000x reference)
//
#include <hip/hip_runtime.h>
#include <math.h>

#define TS 49
#define LOG49 3.8918202981106265f
#define LN2 0.6931471805599453f

typedef short bf16x8 __attribute__((ext_vector_type(8)));  // 8 bf16 = 4 VGPRs
typedef float f32x4 __attribute__((ext_vector_type(4)));

// ws layout:
//   bytes [0, 8192): B-fragments bf16[nt=4][h=2][lane=64][s=8]
//     value = exp(trans[j][k]-Tmax), j = 4*(lane&15)+nt (state-out position),
//     k = 32*h + 8*(lane>>4) + s (state-in position); zero outside 49x49.
//   byte 8192: float Tmax

__global__ void prep_kernel(const float* __restrict__ tf, const float* __restrict__ w2,
                            const float* __restrict__ b2, float* __restrict__ ws) {
    __shared__ float tr[TS * TS];
    __shared__ float red[256];
    const int tid = threadIdx.x;
    const float w0 = w2[0], w1 = w2[1], w2v = w2[2], w3 = w2[3], w4 = w2[4], w5 = w2[5];
    const float bb = b2[0];
    float lmax = -INFINITY;
    for (int idx = tid; idx < TS * TS; idx += 256) {
        const float* p = tf + idx * 6;
        float s = bb + p[0]*w0 + p[1]*w1 + p[2]*w2v + p[3]*w3 + p[4]*w4 + p[5]*w5;
        tr[idx] = s;
        lmax = fmaxf(lmax, s);
    }
    red[tid] = lmax;
    __syncthreads();
    for (int s = 128; s > 0; s >>= 1) {
        if (tid < s) red[tid] = fmaxf(red[tid], red[tid + s]);
        __syncthreads();
    }
    const float Tmax = red[0];
    __syncthreads();
    unsigned short* B = (unsigned short*)ws;
    for (int idx = tid; idx < 4096; idx += 256) {
        const int s  = idx & 7;
        const int l  = (idx >> 3) & 63;
        const int h  = (idx >> 9) & 1;
        const int nt = idx >> 10;
        const int j = 4 * (l & 15) + nt;
        const int k = 32 * h + 8 * (l >> 4) + s;
        float v = (j < TS && k < TS) ? __expf(tr[j * TS + k] - Tmax) : 0.0f;
        unsigned bts = __float_as_uint(v);
        B[idx] = (unsigned short)((bts + 0x7FFFu + ((bts >> 16) & 1u)) >> 16);  // rne bf16
    }
    if (tid == 0) ((float*)ws)[2048] = Tmax;  // byte 8192
}

__device__ __forceinline__ unsigned cvtpk_bf16(float lo, float hi) {
    unsigned d;  // D[15:0] = bf16(lo), D[31:16] = bf16(hi)
    asm("v_cvt_pk_bf16_f32 %0, %1, %2" : "=v"(d) : "v"(lo), "v"(hi));
    return d;
}

// One wave = 16 chains. v[nt][t]: chain = 4*(l>>4)+t, state position p = 4*(l&15)+nt.
// LDS chain-major [16][64 bf16] with XOR swizzle byte ^= ((chain&7)<<4):
//   write: b64 of 4 adjacent positions per chain; read: conflict-free b128 A-frags.
__global__ __launch_bounds__(64) void crf_fwd(const float* __restrict__ emis,
                                              const unsigned short* __restrict__ wsB,
                                              float* __restrict__ out, int L) {
    __shared__ __align__(16) unsigned short V16[1024];
    const int l = threadIdx.x, g = l >> 4, c0 = l & 15;
    const int b0 = blockIdx.x * 16;
    const float Tmax = ((const float*)wsB)[2048];

    bf16x8 Bf[4][2];
    {
        const bf16x8* Bt = (const bf16x8*)wsB;
        #pragma unroll
        for (int nt = 0; nt < 4; ++nt)
            #pragma unroll
            for (int h = 0; h < 2; ++h) Bf[nt][h] = Bt[(nt * 2 + h) * 64 + l];
    }

    const float* eb[4];
    #pragma unroll
    for (int t = 0; t < 4; ++t) eb[t] = emis + (size_t)(b0 + 4 * g + t) * L * TS;

    int jp[4];
    #pragma unroll
    for (int nt = 0; nt < 4; ++nt) jp[nt] = (4 * c0 + nt + 48) % 49;  // rolled emit col

    int wi[4];
    #pragma unroll
    for (int t = 0; t < 4; ++t) {
        const int ch = 4 * g + t;
        wi[t] = ch * 16 + (c0 ^ ((ch & 7) << 1));  // uint2 index, swizzled
    }
    const int ra0 = c0 * 8 + (g ^ (c0 & 7));        // bf16x8 index, k 0..31
    const int ra1 = c0 * 8 + ((4 + g) ^ (c0 & 7));  // k 32..63

    uint2* const Vw = (uint2*)V16;
    const bf16x8* const Vr = (const bf16x8*)V16;

    // init: V_0 = exp(emit[:,0,rolled]); dead positions (p>=49) = 0
    float v[4][4];
    #pragma unroll
    for (int nt = 0; nt < 4; ++nt) {
        const bool live = (4 * c0 + nt) < TS;
        #pragma unroll
        for (int t = 0; t < 4; ++t) v[nt][t] = live ? __expf(eb[t][jp[nt]]) : 0.0f;
    }

    // depth-2 emission prefetch
    float pfA[4][4], pfB[4][4];
    #pragma unroll
    for (int nt = 0; nt < 4; ++nt)
        #pragma unroll
        for (int t = 0; t < 4; ++t) {
            pfA[nt][t] = eb[t][TS + jp[nt]];
            pfB[nt][t] = eb[t][2 * TS + jp[nt]];
        }

    float sc[4]   = {0.f, 0.f, 0.f, 0.f};
    float fac[4]  = {1.f, 1.f, 1.f, 1.f};
    float pend[4] = {0.f, 0.f, 0.f, 0.f};

#define STEP(I, PF, DO_COMPUTE, DO_APPLY) do {                                        \
    /* 1: pack v -> bf16 pairs, 4 x ds_write_b64 (swizzled) */                        \
    _Pragma("unroll")                                                                 \
    for (int t = 0; t < 4; ++t) {                                                     \
        uint2 u;                                                                      \
        u.x = cvtpk_bf16(v[0][t], v[1][t]);                                           \
        u.y = cvtpk_bf16(v[2][t], v[3][t]);                                           \
        Vw[wi[t]] = u;                                                                \
    }                                                                                 \
    /* 2: ee for this step (PF loaded 2 steps ago) - pads write->read latency */      \
    float ee[4][4];                                                                   \
    _Pragma("unroll")                                                                 \
    for (int nt = 0; nt < 4; ++nt)                                                    \
        _Pragma("unroll")                                                             \
        for (int t = 0; t < 4; ++t) ee[nt][t] = __expf(PF[nt][t]);                    \
    /* 3: prefetch step I+2 */                                                        \
    if ((I) + 2 < L) {                                                                \
        const int off = ((I) + 2) * TS;                                               \
        _Pragma("unroll")                                                             \
        for (int nt = 0; nt < 4; ++nt)                                                \
            _Pragma("unroll")                                                         \
            for (int t = 0; t < 4; ++t) PF[nt][t] = eb[t][off + jp[nt]];              \
    }                                                                                 \
    asm volatile("" ::: "memory");                                                    \
    /* 4: A-fragments, conflict-free b128 */                                          \
    const bf16x8 A0 = Vr[ra0];                                                        \
    const bf16x8 A1 = Vr[ra1];                                                        \
    asm volatile("" ::: "memory");                                                    \
    /* 5+6: MFMA and emission/renorm multiply */                                      \
    _Pragma("unroll")                                                                 \
    for (int nt = 0; nt < 4; ++nt) {                                                  \
        f32x4 acc = {0.f, 0.f, 0.f, 0.f};                                             \
        acc = __builtin_amdgcn_mfma_f32_16x16x32_bf16(A0, Bf[nt][0], acc, 0, 0, 0);   \
        acc = __builtin_amdgcn_mfma_f32_16x16x32_bf16(A1, Bf[nt][1], acc, 0, 0, 0);   \
        _Pragma("unroll")                                                             \
        for (int t = 0; t < 4; ++t) {                                                 \
            float nv = acc[t] * ee[nt][t];                                            \
            if (DO_APPLY) nv *= fac[t];                                               \
            v[nt][t] = nv;                                                            \
        }                                                                             \
    }                                                                                 \
    if (DO_APPLY) {                                                                   \
        _Pragma("unroll")                                                             \
        for (int t = 0; t < 4; ++t) sc[t] += pend[t];                                 \
    }                                                                                 \
    /* 7: deferred renorm factor (consumed next step; shfl chain off critical path) */\
    if (DO_COMPUTE) {                                                                 \
        _Pragma("unroll")                                                             \
        for (int t = 0; t < 4; ++t) {                                                 \
            float mx = fmaxf(fmaxf(v[0][t], v[1][t]), fmaxf(v[2][t], v[3][t]));       \
            mx = fmaxf(mx, __shfl_xor(mx, 1, 64));                                    \
            mx = fmaxf(mx, __shfl_xor(mx, 2, 64));                                    \
            mx = fmaxf(mx, __shfl_xor(mx, 4, 64));                                    \
            mx = fmaxf(mx, __shfl_xor(mx, 8, 64));                                    \
            const unsigned ex = __float_as_uint(mx) >> 23;                            \
            fac[t]  = __uint_as_float((254u - ex) << 23);                             \
            pend[t] = (float)((int)ex - 127) * LN2;                                   \
        }                                                                             \
    }                                                                                 \
} while (0)

    int i = 1;
    for (; i + 1 < L; i += 2) {
        STEP(i, pfA, 1, 0);      // odd: compute renorm factor
        STEP(i + 1, pfB, 0, 1);  // even: apply it
    }
    if (i < L) STEP(i, pfA, 0, 0);  // tail
#undef STEP

    // final: alpha[chain] = sc + log(sum_p V) + log49 + (L-1)*Tmax
    float res[4];
    #pragma unroll
    for (int t = 0; t < 4; ++t) {
        float s = (v[0][t] + v[1][t]) + (v[2][t] + v[3][t]);
        s += __shfl_xor(s, 1, 64);
        s += __shfl_xor(s, 2, 64);
        s += __shfl_xor(s, 4, 64);
        s += __shfl_xor(s, 8, 64);
        res[t] = sc[t] + __logf(s) + LOG49 + (float)(L - 1) * Tmax;
    }
    if (c0 == 0) {
        #pragma unroll
        for (int t = 0; t < 4; ++t) out[b0 + 4 * g + t] = res[t];
    }
}

extern "C" void kernel_launch(void* const* d_in, const int* in_sizes, int n_in,
                              void* d_out, int out_size, void* d_ws, size_t ws_size,
                              hipStream_t stream) {
    const float* emis = (const float*)d_in[0];
    const float* tf   = (const float*)d_in[1];
    const float* w2   = (const float*)d_in[2];
    const float* b2   = (const float*)d_in[3];
    float* out = (float*)d_out;
    float* ws  = (float*)d_ws;

    const int B = out_size;                // 8192
    const int L = in_sizes[0] / (B * TS);  // 48

    prep_kernel<<<1, 256, 0, stream>>>(tf, w2, b2, ws);
    crf_fwd<<<B / 16, 64, 0, stream>>>(emis, (const unsigned short*)ws, out, L);
}